// Round 4
// baseline (210.062 us; speedup 1.0000x reference)
//
#include <hip/hip_runtime.h>

// PositionalEncoder: out[k] = sum_j ((1 - j/J) - (k/d)*(1 - 2j/J)) * E[j,k]
// j = 1..J (row+1), k = 1..d (col+1). E row-major [J, D] fp32.
//
// R4 theory: R3's stage1 ran at ~2 TB/s consumed because the grid (512
// blocks) gave only 16 waves/CU -> not enough loads in flight (latency-
// bound, not BW-bound). Fix: 1024 blocks = 32 waves/CU (full occupancy,
// __launch_bounds__(512,8) pins VGPR<=64), and contiguous 16-row blocks
// for DRAM page locality. Keep 4 independent float4 loads in flight per
// iteration; #pragma unroll 1 stops the compiler hoisting all 16 loads
// (would push VGPR past 64 -> occupancy halves).

constexpr int D_COLS = 2048;
constexpr int J_ROWS = 16384;
constexpr int T1  = 512;            // 512 threads x float4 spans one full row
constexpr int NB1 = 1024;           // stage-1 blocks -> 32 waves/CU
constexpr int RPB = J_ROWS / NB1;   // 16 contiguous rows per block

__global__ __launch_bounds__(T1, 8) void pe_stage1(const float* __restrict__ E,
                                                   float* __restrict__ ws) {
    const int tid  = threadIdx.x;
    const int col0 = tid * 4;
    const int b    = blockIdx.x;
    const int row0 = b * RPB;
    const float invJ = 1.0f / (float)J_ROWS;
    const float invD = 1.0f / (float)D_COLS;
    const float c0 = (float)(col0 + 1) * invD;
    const float c1 = (float)(col0 + 2) * invD;
    const float c2 = (float)(col0 + 3) * invD;
    const float c3 = (float)(col0 + 4) * invD;

    const float* base = E + (size_t)row0 * D_COLS + col0;

    float4 acc = make_float4(0.f, 0.f, 0.f, 0.f);
    #pragma unroll 1
    for (int it = 0; it < RPB / 4; ++it) {          // 4 iterations x 4 rows
        const int r = it * 4;                        // row offset within block
        // 4 independent loads of 4 contiguous rows (32 KB/block/iter)
        const float4 e0 = *reinterpret_cast<const float4*>(base + (size_t)(r + 0) * D_COLS);
        const float4 e1 = *reinterpret_cast<const float4*>(base + (size_t)(r + 1) * D_COLS);
        const float4 e2 = *reinterpret_cast<const float4*>(base + (size_t)(r + 2) * D_COLS);
        const float4 e3 = *reinterpret_cast<const float4*>(base + (size_t)(r + 3) * D_COLS);

        const float j0 = (float)(row0 + r + 1);
        const float j1 = j0 + 1.0f, j2 = j0 + 2.0f, j3 = j0 + 3.0f;
        const float a0 = fmaf(-j0, invJ, 1.0f), bb0 = fmaf(-2.f * j0, invJ, 1.0f);
        const float a1 = fmaf(-j1, invJ, 1.0f), bb1 = fmaf(-2.f * j1, invJ, 1.0f);
        const float a2 = fmaf(-j2, invJ, 1.0f), bb2 = fmaf(-2.f * j2, invJ, 1.0f);
        const float a3 = fmaf(-j3, invJ, 1.0f), bb3 = fmaf(-2.f * j3, invJ, 1.0f);

        acc.x = fmaf(fmaf(-c0, bb0, a0), e0.x, acc.x);
        acc.y = fmaf(fmaf(-c1, bb0, a0), e0.y, acc.y);
        acc.z = fmaf(fmaf(-c2, bb0, a0), e0.z, acc.z);
        acc.w = fmaf(fmaf(-c3, bb0, a0), e0.w, acc.w);
        acc.x = fmaf(fmaf(-c0, bb1, a1), e1.x, acc.x);
        acc.y = fmaf(fmaf(-c1, bb1, a1), e1.y, acc.y);
        acc.z = fmaf(fmaf(-c2, bb1, a1), e1.z, acc.z);
        acc.w = fmaf(fmaf(-c3, bb1, a1), e1.w, acc.w);
        acc.x = fmaf(fmaf(-c0, bb2, a2), e2.x, acc.x);
        acc.y = fmaf(fmaf(-c1, bb2, a2), e2.y, acc.y);
        acc.z = fmaf(fmaf(-c2, bb2, a2), e2.z, acc.z);
        acc.w = fmaf(fmaf(-c3, bb2, a2), e2.w, acc.w);
        acc.x = fmaf(fmaf(-c0, bb3, a3), e3.x, acc.x);
        acc.y = fmaf(fmaf(-c1, bb3, a3), e3.y, acc.y);
        acc.z = fmaf(fmaf(-c2, bb3, a3), e3.z, acc.z);
        acc.w = fmaf(fmaf(-c3, bb3, a3), e3.w, acc.w);
    }

    // Transposed partials: ws[col][b], contiguous per column for stage2.
    // Scattered 4B stores, fire-and-forget, 8 MiB total -> L2-absorbed.
    ws[(size_t)(col0 + 0) * NB1 + b] = acc.x;
    ws[(size_t)(col0 + 1) * NB1 + b] = acc.y;
    ws[(size_t)(col0 + 2) * NB1 + b] = acc.z;
    ws[(size_t)(col0 + 3) * NB1 + b] = acc.w;
}

// One wave per column: 1024 contiguous partials = 4 KB = 64 lanes x 4 float4.
__global__ __launch_bounds__(256) void pe_stage2(const float* __restrict__ ws,
                                                 float* __restrict__ out) {
    const int wave = threadIdx.x >> 6;
    const int lane = threadIdx.x & 63;
    const int col  = blockIdx.x * 4 + wave;
    const float4* p = reinterpret_cast<const float4*>(ws + (size_t)col * NB1);
    const float4 v0 = p[lane];
    const float4 v1 = p[lane + 64];
    const float4 v2 = p[lane + 128];
    const float4 v3 = p[lane + 192];
    float s = (((v0.x + v0.y) + (v0.z + v0.w)) + ((v1.x + v1.y) + (v1.z + v1.w)))
            + (((v2.x + v2.y) + (v2.z + v2.w)) + ((v3.x + v3.y) + (v3.z + v3.w)));
    #pragma unroll
    for (int off = 32; off > 0; off >>= 1)
        s += __shfl_down(s, off, 64);
    if (lane == 0) out[col] = s;
}

extern "C" void kernel_launch(void* const* d_in, const int* in_sizes, int n_in,
                              void* d_out, int out_size, void* d_ws, size_t ws_size,
                              hipStream_t stream) {
    const float* E = (const float*)d_in[0];
    float* out = (float*)d_out;
    float* ws = (float*)d_ws;   // needs 2048*1024*4 = 8 MiB (harness gives far more)
    (void)in_sizes; (void)n_in; (void)out_size; (void)ws_size;

    pe_stage1<<<NB1, T1, 0, stream>>>(E, ws);
    pe_stage2<<<D_COLS / 4, 256, 0, stream>>>(ws, out);
}

// Round 5
// 194.186 us; speedup vs baseline: 1.0818x; 1.0818x over previous
//
#include <hip/hip_runtime.h>

// PositionalEncoder: out[k] = sum_j ((1 - j/J) - (k/d)*(1 - 2j/J)) * E[j,k]
// j = 1..J (row+1), k = 1..d (col+1). E row-major [J, D] fp32.
//
// R5 theory: R3/R4's transposed partial store (lane stride 4 KB) caused
// ~10x write amplification (WRITE_SIZE 84.5 MB for 8 MiB of payload:
// every 4 B store write-allocates a 64 B poisoned line) and the L2 RMW
// storm throttled the kernel to ~2 TB/s. Fix: all reduction levels write
// ROW-MAJOR, float4-coalesced, full-line stores:
//   stage1: [1024][2048] partials (8 MiB)  -> coalesced writes
//   stage2: 64 blocks sum 16 rows each -> [64][2048] (512 KB), coalesced
//   stage3: 1 thread/column sums 64 L2-hot scalars -> out (overwrites all)

constexpr int D_COLS = 2048;
constexpr int J_ROWS = 16384;
constexpr int T1  = 512;            // 512 threads x float4 spans one full row
constexpr int NB1 = 1024;           // stage-1 blocks; 16 contiguous rows each
constexpr int RPB = J_ROWS / NB1;   // 16
constexpr int NB2 = 64;             // stage-2 blocks; 16 ws-rows each

__global__ __launch_bounds__(T1, 8) void pe_stage1(const float* __restrict__ E,
                                                   float* __restrict__ ws) {
    const int tid  = threadIdx.x;
    const int col0 = tid * 4;
    const int b    = blockIdx.x;
    const int row0 = b * RPB;
    const float invJ = 1.0f / (float)J_ROWS;
    const float invD = 1.0f / (float)D_COLS;
    const float c0 = (float)(col0 + 1) * invD;
    const float c1 = (float)(col0 + 2) * invD;
    const float c2 = (float)(col0 + 3) * invD;
    const float c3 = (float)(col0 + 4) * invD;

    const float* base = E + (size_t)row0 * D_COLS + col0;

    float4 acc = make_float4(0.f, 0.f, 0.f, 0.f);
    #pragma unroll 1
    for (int it = 0; it < RPB / 4; ++it) {          // 4 iterations x 4 rows
        const int r = it * 4;
        const float4 e0 = *reinterpret_cast<const float4*>(base + (size_t)(r + 0) * D_COLS);
        const float4 e1 = *reinterpret_cast<const float4*>(base + (size_t)(r + 1) * D_COLS);
        const float4 e2 = *reinterpret_cast<const float4*>(base + (size_t)(r + 2) * D_COLS);
        const float4 e3 = *reinterpret_cast<const float4*>(base + (size_t)(r + 3) * D_COLS);

        const float j0 = (float)(row0 + r + 1);
        const float j1 = j0 + 1.0f, j2 = j0 + 2.0f, j3 = j0 + 3.0f;
        const float a0 = fmaf(-j0, invJ, 1.0f), bb0 = fmaf(-2.f * j0, invJ, 1.0f);
        const float a1 = fmaf(-j1, invJ, 1.0f), bb1 = fmaf(-2.f * j1, invJ, 1.0f);
        const float a2 = fmaf(-j2, invJ, 1.0f), bb2 = fmaf(-2.f * j2, invJ, 1.0f);
        const float a3 = fmaf(-j3, invJ, 1.0f), bb3 = fmaf(-2.f * j3, invJ, 1.0f);

        acc.x = fmaf(fmaf(-c0, bb0, a0), e0.x, acc.x);
        acc.y = fmaf(fmaf(-c1, bb0, a0), e0.y, acc.y);
        acc.z = fmaf(fmaf(-c2, bb0, a0), e0.z, acc.z);
        acc.w = fmaf(fmaf(-c3, bb0, a0), e0.w, acc.w);
        acc.x = fmaf(fmaf(-c0, bb1, a1), e1.x, acc.x);
        acc.y = fmaf(fmaf(-c1, bb1, a1), e1.y, acc.y);
        acc.z = fmaf(fmaf(-c2, bb1, a1), e1.z, acc.z);
        acc.w = fmaf(fmaf(-c3, bb1, a1), e1.w, acc.w);
        acc.x = fmaf(fmaf(-c0, bb2, a2), e2.x, acc.x);
        acc.y = fmaf(fmaf(-c1, bb2, a2), e2.y, acc.y);
        acc.z = fmaf(fmaf(-c2, bb2, a2), e2.z, acc.z);
        acc.w = fmaf(fmaf(-c3, bb2, a2), e2.w, acc.w);
        acc.x = fmaf(fmaf(-c0, bb3, a3), e3.x, acc.x);
        acc.y = fmaf(fmaf(-c1, bb3, a3), e3.y, acc.y);
        acc.z = fmaf(fmaf(-c2, bb3, a3), e3.z, acc.z);
        acc.w = fmaf(fmaf(-c3, bb3, a3), e3.w, acc.w);
    }

    // Row-major, float4-coalesced: block b's 512 threads cover one full
    // 8 KB line-aligned row -> full-line stores, no write-allocate fetch.
    *reinterpret_cast<float4*>(ws + (size_t)b * D_COLS + col0) = acc;
}

// stage2: block b sums ws rows [16b, 16b+16) -> ws2[b][*]. All coalesced.
__global__ __launch_bounds__(T1) void pe_stage2(const float* __restrict__ ws,
                                                float* __restrict__ ws2) {
    const int col0 = threadIdx.x * 4;
    const int b    = blockIdx.x;
    const float* base = ws + (size_t)(b * (NB1 / NB2)) * D_COLS + col0;
    float4 acc = make_float4(0.f, 0.f, 0.f, 0.f);
    #pragma unroll
    for (int r = 0; r < NB1 / NB2; ++r) {
        const float4 v = *reinterpret_cast<const float4*>(base + (size_t)r * D_COLS);
        acc.x += v.x; acc.y += v.y; acc.z += v.z; acc.w += v.w;
    }
    *reinterpret_cast<float4*>(ws2 + (size_t)b * D_COLS + col0) = acc;
}

// stage3: thread k sums ws2[r][k], r=0..63 (L2-hot, 4-way ILP). Writes out.
__global__ __launch_bounds__(T1) void pe_stage3(const float* __restrict__ ws2,
                                                float* __restrict__ out) {
    const int k = blockIdx.x * T1 + threadIdx.x;
    float s0 = 0.f, s1 = 0.f, s2 = 0.f, s3 = 0.f;
    #pragma unroll
    for (int r = 0; r < NB2; r += 4) {
        s0 += ws2[(size_t)(r + 0) * D_COLS + k];
        s1 += ws2[(size_t)(r + 1) * D_COLS + k];
        s2 += ws2[(size_t)(r + 2) * D_COLS + k];
        s3 += ws2[(size_t)(r + 3) * D_COLS + k];
    }
    out[k] = (s0 + s1) + (s2 + s3);
}

extern "C" void kernel_launch(void* const* d_in, const int* in_sizes, int n_in,
                              void* d_out, int out_size, void* d_ws, size_t ws_size,
                              hipStream_t stream) {
    const float* E = (const float*)d_in[0];
    float* out = (float*)d_out;
    float* ws  = (float*)d_ws;                          // 8 MiB partials
    float* ws2 = ws + (size_t)NB1 * D_COLS;             // +512 KB second level
    (void)in_sizes; (void)n_in; (void)out_size; (void)ws_size;  // ws_size ~512 MB >> 8.5 MiB

    pe_stage1<<<NB1, T1, 0, stream>>>(E, ws);
    pe_stage2<<<NB2, T1, 0, stream>>>(ws, ws2);
    pe_stage3<<<D_COLS / T1, T1, 0, stream>>>(ws2, out);
}

// Round 7
// 184.164 us; speedup vs baseline: 1.1406x; 1.0544x over previous
//
#include <hip/hip_runtime.h>

// PositionalEncoder: out[k] = sum_j ((1 - j/J) - (k/d)*(1 - 2j/J)) * E[j,k]
// j = 1..J (row+1), k = 1..d (col+1). E row-major [J, D] fp32.
//
// R7 = R6 with the compile fix: __builtin_nontemporal_load needs a clang
// ext_vector_type pointer (HIP's float4 is a struct -> rejected).
//
// R6 theory under test: R5's stage1 read 128 MiB at only ~2.2 TB/s.
// Suspected: (a) channel phase-locking — contiguous-region-per-block makes
// the grid's instantaneous address set a 128 KiB-strided comb -> few HBM
// channels live; (b) dirty-LLC eviction tax — harness's 512 MB 0xAA poison
// leaves MALL dirty; allocating read misses force dirty writebacks. Fix:
//   - grid-SWEEP: iteration it, block b reads 4 contiguous rows at
//     (it*1024+b)*4 -> instantaneous window = one contiguous 32 MiB span.
//   - nontemporal loads for E: probe caches, no allocate on miss.
// Reduction tree (R5, proven clean): ws[1024][2048] -> 64 rows -> out,
// all float4-coalesced full-line stores.

constexpr int D_COLS = 2048;
constexpr int J_ROWS = 16384;
constexpr int T1  = 512;            // 512 threads x float4 spans one full row
constexpr int NB1 = 1024;           // stage-1 blocks; 32 waves/CU
constexpr int NB2 = 64;             // stage-2 blocks

typedef float vfloat4 __attribute__((ext_vector_type(4)));

__global__ __launch_bounds__(T1, 8) void pe_stage1(const float* __restrict__ E,
                                                   float* __restrict__ ws) {
    const int tid  = threadIdx.x;
    const int col0 = tid * 4;
    const int b    = blockIdx.x;
    const float invJ = 1.0f / (float)J_ROWS;
    const float invD = 1.0f / (float)D_COLS;
    const float c0 = (float)(col0 + 1) * invD;
    const float c1 = (float)(col0 + 2) * invD;
    const float c2 = (float)(col0 + 3) * invD;
    const float c3 = (float)(col0 + 4) * invD;

    float ax = 0.f, ay = 0.f, az = 0.f, aw = 0.f;
    // Sweep: per iteration the WHOLE GRID covers rows [it*4096, it*4096+4096)
    // contiguously; block b owns 4 adjacent rows inside that window.
    #pragma unroll 1
    for (int it = 0; it < J_ROWS / (4 * NB1); ++it) {   // 4 iterations
        const int r0 = (it * NB1 + b) * 4;
        const float* base = E + (size_t)r0 * D_COLS + col0;
        const vfloat4 e0 = __builtin_nontemporal_load(
            reinterpret_cast<const vfloat4*>(base + (size_t)0 * D_COLS));
        const vfloat4 e1 = __builtin_nontemporal_load(
            reinterpret_cast<const vfloat4*>(base + (size_t)1 * D_COLS));
        const vfloat4 e2 = __builtin_nontemporal_load(
            reinterpret_cast<const vfloat4*>(base + (size_t)2 * D_COLS));
        const vfloat4 e3 = __builtin_nontemporal_load(
            reinterpret_cast<const vfloat4*>(base + (size_t)3 * D_COLS));

        const float j0 = (float)(r0 + 1);
        const float j1 = j0 + 1.0f, j2 = j0 + 2.0f, j3 = j0 + 3.0f;
        const float a0 = fmaf(-j0, invJ, 1.0f), bb0 = fmaf(-2.f * j0, invJ, 1.0f);
        const float a1 = fmaf(-j1, invJ, 1.0f), bb1 = fmaf(-2.f * j1, invJ, 1.0f);
        const float a2 = fmaf(-j2, invJ, 1.0f), bb2 = fmaf(-2.f * j2, invJ, 1.0f);
        const float a3 = fmaf(-j3, invJ, 1.0f), bb3 = fmaf(-2.f * j3, invJ, 1.0f);

        ax = fmaf(fmaf(-c0, bb0, a0), e0.x, ax);
        ay = fmaf(fmaf(-c1, bb0, a0), e0.y, ay);
        az = fmaf(fmaf(-c2, bb0, a0), e0.z, az);
        aw = fmaf(fmaf(-c3, bb0, a0), e0.w, aw);
        ax = fmaf(fmaf(-c0, bb1, a1), e1.x, ax);
        ay = fmaf(fmaf(-c1, bb1, a1), e1.y, ay);
        az = fmaf(fmaf(-c2, bb1, a1), e1.z, az);
        aw = fmaf(fmaf(-c3, bb1, a1), e1.w, aw);
        ax = fmaf(fmaf(-c0, bb2, a2), e2.x, ax);
        ay = fmaf(fmaf(-c1, bb2, a2), e2.y, ay);
        az = fmaf(fmaf(-c2, bb2, a2), e2.z, az);
        aw = fmaf(fmaf(-c3, bb2, a2), e2.w, aw);
        ax = fmaf(fmaf(-c0, bb3, a3), e3.x, ax);
        ay = fmaf(fmaf(-c1, bb3, a3), e3.y, ay);
        az = fmaf(fmaf(-c2, bb3, a3), e3.z, az);
        aw = fmaf(fmaf(-c3, bb3, a3), e3.w, aw);
    }

    // Row-major, float4-coalesced full-line store (R5 lesson: no scatter).
    vfloat4 acc; acc.x = ax; acc.y = ay; acc.z = az; acc.w = aw;
    *reinterpret_cast<vfloat4*>(ws + (size_t)b * D_COLS + col0) = acc;
}

// stage2: block b sums ws rows [16b, 16b+16) -> ws2[b][*]. All coalesced.
__global__ __launch_bounds__(T1) void pe_stage2(const float* __restrict__ ws,
                                                float* __restrict__ ws2) {
    const int col0 = threadIdx.x * 4;
    const int b    = blockIdx.x;
    const float* base = ws + (size_t)(b * (NB1 / NB2)) * D_COLS + col0;
    vfloat4 acc = (vfloat4)0.f;
    #pragma unroll
    for (int r = 0; r < NB1 / NB2; ++r) {
        const vfloat4 v = *reinterpret_cast<const vfloat4*>(base + (size_t)r * D_COLS);
        acc += v;
    }
    *reinterpret_cast<vfloat4*>(ws2 + (size_t)b * D_COLS + col0) = acc;
}

// stage3: thread k sums ws2[r][k], r=0..63 (L2-hot, 4-way ILP). Writes out.
__global__ __launch_bounds__(T1) void pe_stage3(const float* __restrict__ ws2,
                                                float* __restrict__ out) {
    const int k = blockIdx.x * T1 + threadIdx.x;
    float s0 = 0.f, s1 = 0.f, s2 = 0.f, s3 = 0.f;
    #pragma unroll
    for (int r = 0; r < NB2; r += 4) {
        s0 += ws2[(size_t)(r + 0) * D_COLS + k];
        s1 += ws2[(size_t)(r + 1) * D_COLS + k];
        s2 += ws2[(size_t)(r + 2) * D_COLS + k];
        s3 += ws2[(size_t)(r + 3) * D_COLS + k];
    }
    out[k] = (s0 + s1) + (s2 + s3);
}

extern "C" void kernel_launch(void* const* d_in, const int* in_sizes, int n_in,
                              void* d_out, int out_size, void* d_ws, size_t ws_size,
                              hipStream_t stream) {
    const float* E = (const float*)d_in[0];
    float* out = (float*)d_out;
    float* ws  = (float*)d_ws;                          // 8 MiB partials
    float* ws2 = ws + (size_t)NB1 * D_COLS;             // +512 KB second level
    (void)in_sizes; (void)n_in; (void)out_size; (void)ws_size;

    pe_stage1<<<NB1, T1, 0, stream>>>(E, ws);
    pe_stage2<<<NB2, T1, 0, stream>>>(ws, ws2);
    pe_stage3<<<D_COLS / T1, T1, 0, stream>>>(ws2, out);
}